// Round 1
// baseline (780.790 us; speedup 1.0000x reference)
//
#include <hip/hip_runtime.h>

// MIPTCell: proj = e @ [Wp;Wth;Wr;Wi]^T + b  (M=8192, N=4*2048, K=2048, bf16 MFMA)
// fused with sigmoid/rot/gate epilogue. fp32 in/out; bf16 operands staged in d_ws.

typedef float f32x4 __attribute__((ext_vector_type(4)));
typedef __bf16 bf16x8 __attribute__((ext_vector_type(8)));
typedef short short8 __attribute__((ext_vector_type(8)));

__device__ __forceinline__ unsigned short f2bf(float f) {
    unsigned u = __float_as_uint(f);
    u += 0x7fffu + ((u >> 16) & 1u);   // round-to-nearest-even
    return (unsigned short)(u >> 16);
}

// fp32 -> bf16 convert, 4 elements/thread (float4 in, ushort4 out)
__global__ __launch_bounds__(256) void cvt_kernel(const float* __restrict__ src,
                                                  unsigned short* __restrict__ dst,
                                                  int n4) {
    int i = blockIdx.x * 256 + threadIdx.x;
    if (i < n4) {
        float4 v = ((const float4*)src)[i];
        ushort4 o;
        o.x = f2bf(v.x); o.y = f2bf(v.y); o.z = f2bf(v.z); o.w = f2bf(v.w);
        ((ushort4*)dst)[i] = o;
    }
}

__device__ __forceinline__ void load16_lds(const unsigned short* g, unsigned short* l) {
    __builtin_amdgcn_global_load_lds((const __attribute__((address_space(1))) void*)g,
                                     (__attribute__((address_space(3))) void*)l,
                                     16, 0, 0);
}

__device__ __forceinline__ bf16x8 ldfrag(const unsigned short* p) {
    return __builtin_bit_cast(bf16x8, *(const short8*)p);
}

// Block tile: 128 rows (e) x 32 d-cols x 4 matrices (=128 effective N cols).
// 4 waves; wave w owns rows [w*32, w*32+32), all 128 eff-cols -> 2x8 MFMA tiles.
// Eff col n_eff in [0,128): chunk = n_eff>>5 (0=p,1=theta,2=re,3=im), d-col = n0 + (n_eff&31).
__global__ __launch_bounds__(256) void mipt_main(
    const unsigned short* __restrict__ E,   // [8192][2048] bf16
    const unsigned short* __restrict__ W,   // [8192][2048] bf16 (Wp;Wth;Wr;Wi)
    const float* __restrict__ b_p, const float* __restrict__ b_th,
    const float* __restrict__ b_r, const float* __restrict__ b_i,
    const float* __restrict__ h_prev,       // [8192][4096] fp32
    float* __restrict__ out)                // [8192][4096] fp32
{
    __shared__ unsigned short As[128 * 32];
    __shared__ unsigned short Bs[128 * 32];

    const int tid  = threadIdx.x;
    const int wave = tid >> 6;
    const int lane = tid & 63;
    const int m0 = blockIdx.x * 128;
    const int n0 = blockIdx.y * 32;

    f32x4 acc[2][8];
#pragma unroll
    for (int i = 0; i < 2; ++i)
#pragma unroll
        for (int j = 0; j < 8; ++j)
            acc[i][j] = (f32x4){0.f, 0.f, 0.f, 0.f};

    // ---- staging addressing (global_load_lds: wave-uniform LDS base + lane*16B) ----
    const int srow = lane >> 2;        // 0..15 (4 lanes per 64B row-chunk)
    const int scol = (lane & 3) * 8;   // k element offset
    // A: wave w stages rows w*32 + s*16 + srow (its own compute rows)
    const unsigned short* Ag0 = E + (size_t)(m0 + wave * 32 + srow) * 2048 + scol;
    const unsigned short* Ag1 = Ag0 + (size_t)16 * 2048;
    unsigned short* Al0 = As + (wave * 32) * 32;
    unsigned short* Al1 = As + (wave * 32 + 16) * 32;
    // B: Bs row rb = w*32 + s*16 + srow; chunk = w; W_cat row = w*2048 + n0 + (rb&31)
    const unsigned short* Bg0 = W + (size_t)(wave * 2048 + n0 + srow) * 2048 + scol;
    const unsigned short* Bg1 = Bg0 + (size_t)16 * 2048;
    unsigned short* Bl0 = Bs + (wave * 32) * 32;
    unsigned short* Bl1 = Bs + (wave * 32 + 16) * 32;

    // ---- fragment read addressing ----
    const int fr = lane & 15;          // m (A) / n (B) index within 16-tile
    const int fk = (lane >> 4) * 8;    // k element offset
    const unsigned short* Ap = As + (wave * 32 + fr) * 32 + fk;  // +16*32 per ti
    const unsigned short* Bp = Bs + fr * 32 + fk;                // +16*32 per tj

#pragma unroll 1
    for (int kt = 0; kt < 64; ++kt) {
        const int k0 = kt * 32;
        load16_lds(Ag0 + k0, Al0);
        load16_lds(Ag1 + k0, Al1);
        load16_lds(Bg0 + k0, Bl0);
        load16_lds(Bg1 + k0, Bl1);
        __syncthreads();   // drains vmcnt -> staged data visible

        bf16x8 a0 = ldfrag(Ap);
        bf16x8 a1 = ldfrag(Ap + 16 * 32);
        bf16x8 b[8];
#pragma unroll
        for (int tj = 0; tj < 8; ++tj) b[tj] = ldfrag(Bp + tj * 16 * 32);

#pragma unroll
        for (int tj = 0; tj < 8; ++tj) {
            acc[0][tj] = __builtin_amdgcn_mfma_f32_16x16x32_bf16(a0, b[tj], acc[0][tj], 0, 0, 0);
            acc[1][tj] = __builtin_amdgcn_mfma_f32_16x16x32_bf16(a1, b[tj], acc[1][tj], 0, 0, 0);
        }
        __syncthreads();   // compute done before next stage overwrites
    }

    // ---- fused epilogue: all 4 chunks for (m, c) live in this thread's acc ----
    // C/D layout (16x16x32): col = lane&15 (n, from B), row = (lane>>4)*4 + reg (m, from A)
    const int colb = n0 + (lane & 15);
    const int rowb = m0 + wave * 32 + (lane >> 4) * 4;
#pragma unroll
    for (int tj = 0; tj < 2; ++tj) {
        const int c = colb + tj * 16;
        const float bp = b_p[c], bt = b_th[c], br = b_r[c], bi = b_i[c];
#pragma unroll
        for (int ti = 0; ti < 2; ++ti) {
#pragma unroll
            for (int r = 0; r < 4; ++r) {
                const int m = rowb + ti * 16 + r;
                const float pl  = acc[ti][tj    ][r] + bp;
                const float th  = acc[ti][tj + 2][r] + bt;
                const float ire = acc[ti][tj + 4][r] + br;
                const float iim = acc[ti][tj + 6][r] + bi;
                const float p = 1.f / (1.f + __expf(-pl));
                float s, ct;
                __sincosf(th, &s, &ct);
                const size_t base = (size_t)m * 4096 + c;
                const float hre = h_prev[base];
                const float him = h_prev[base + 2048];
                const float rre = ct * hre - s * him;
                const float rim = s * hre + ct * him;
                out[base]        = (1.f - p) * rre + p * ire;
                out[base + 2048] = (1.f - p) * rim + p * iim;
            }
        }
    }
}

extern "C" void kernel_launch(void* const* d_in, const int* in_sizes, int n_in,
                              void* d_out, int out_size, void* d_ws, size_t ws_size,
                              hipStream_t stream) {
    (void)in_sizes; (void)n_in; (void)out_size; (void)ws_size;
    const float* e_t   = (const float*)d_in[0];
    const float* h_prv = (const float*)d_in[1];
    const float* W_p   = (const float*)d_in[2];
    const float* b_p   = (const float*)d_in[3];
    const float* W_th  = (const float*)d_in[4];
    const float* b_th  = (const float*)d_in[5];
    const float* W_r   = (const float*)d_in[6];
    const float* b_r   = (const float*)d_in[7];
    const float* W_i   = (const float*)d_in[8];
    const float* b_i   = (const float*)d_in[9];
    float* out = (float*)d_out;

    // workspace: W_cat bf16 [8192][2048] (32MB) then E bf16 [8192][2048] (32MB)
    unsigned short* Wbf = (unsigned short*)d_ws;
    unsigned short* Ebf = Wbf + (size_t)8192 * 2048;

    const int wn4 = (2048 * 2048) / 4;    // float4 groups per W matrix
    const size_t wstride = (size_t)2048 * 2048;
    cvt_kernel<<<wn4 / 256, 256, 0, stream>>>(W_p,  Wbf,               wn4);
    cvt_kernel<<<wn4 / 256, 256, 0, stream>>>(W_th, Wbf + 1 * wstride, wn4);
    cvt_kernel<<<wn4 / 256, 256, 0, stream>>>(W_r,  Wbf + 2 * wstride, wn4);
    cvt_kernel<<<wn4 / 256, 256, 0, stream>>>(W_i,  Wbf + 3 * wstride, wn4);
    const int en4 = (8192 * 2048) / 4;
    cvt_kernel<<<en4 / 256, 256, 0, stream>>>(e_t, Ebf, en4);

    dim3 grid(64, 64);   // x: m-tiles (128 rows), y: d-col tiles (32 cols)
    mipt_main<<<grid, 256, 0, stream>>>(Ebf, Wbf, b_p, b_th, b_r, b_i, h_prv, out);
}

// Round 2
// 602.976 us; speedup vs baseline: 1.2949x; 1.2949x over previous
//
#include <hip/hip_runtime.h>

// MIPTCell: proj = e @ [Wp;Wth;Wr;Wi]^T + b  (M=8192, N=4*2048, K=2048)
// bf16 32x32x16 MFMA GEMM fused with sigmoid/rot/gate epilogue.
// Block tile: 256 rows x 32 d-cols x 4 matrices (128 eff N), BK=32.
// Wave w owns rows [w*64, w*64+64) x all 128 eff cols -> acc[2][4] f32x16.
// LDS chunk XOR-swizzle (slot = c ^ ((row>>1)&3)) for conflict-free ds_read_b128.

typedef float f32x16 __attribute__((ext_vector_type(16)));
typedef __bf16 bf16x8 __attribute__((ext_vector_type(8)));
typedef short short8 __attribute__((ext_vector_type(8)));

__device__ __forceinline__ unsigned short f2bf(float f) {
    unsigned u = __float_as_uint(f);
    u += 0x7fffu + ((u >> 16) & 1u);   // round-to-nearest-even
    return (unsigned short)(u >> 16);
}

// Fused fp32->bf16 convert for all 5 tensors in ONE launch.
// unit = 8 floats (two float4 loads, one 16B store).
// units: W: 4 * 524288 (= 2048*2048/8 each), then E: 2097152 (= 8192*2048/8).
__global__ __launch_bounds__(256) void cvt_all(
    const float* __restrict__ W_p, const float* __restrict__ W_th,
    const float* __restrict__ W_r, const float* __restrict__ W_i,
    const float* __restrict__ e_t,
    unsigned short* __restrict__ Wbf, unsigned short* __restrict__ Ebf) {
    const long i = (long)blockIdx.x * 256 + threadIdx.x;   // < 4194304
    const float* src;
    unsigned short* dst;
    size_t local;
    if (i < 2097152) {
        const int m = (int)(i >> 19);
        local = (size_t)(i & 524287) * 8;
        src = (m == 0) ? W_p : (m == 1) ? W_th : (m == 2) ? W_r : W_i;
        dst = Wbf + (size_t)m * 4194304 + local;
    } else {
        local = (size_t)(i - 2097152) * 8;
        src = e_t;
        dst = Ebf + local;
    }
    const float4* s4 = (const float4*)(src + local);
    float4 v0 = s4[0], v1 = s4[1];
    ushort4 o0, o1;
    o0.x = f2bf(v0.x); o0.y = f2bf(v0.y); o0.z = f2bf(v0.z); o0.w = f2bf(v0.w);
    o1.x = f2bf(v1.x); o1.y = f2bf(v1.y); o1.z = f2bf(v1.z); o1.w = f2bf(v1.w);
    ((ushort4*)dst)[0] = o0;
    ((ushort4*)dst)[1] = o1;
}

__device__ __forceinline__ void load16_lds(const unsigned short* g, unsigned short* l) {
    __builtin_amdgcn_global_load_lds((const __attribute__((address_space(1))) void*)g,
                                     (__attribute__((address_space(3))) void*)l,
                                     16, 0, 0);
}

__device__ __forceinline__ bf16x8 ldfrag(const unsigned short* p) {
    return __builtin_bit_cast(bf16x8, *(const short8*)p);
}

__global__ __launch_bounds__(256, 2) void mipt_main(
    const unsigned short* __restrict__ E,   // [8192][2048] bf16
    const unsigned short* __restrict__ W,   // [8192][2048] bf16 (Wp;Wth;Wr;Wi)
    const float* __restrict__ b_p, const float* __restrict__ b_th,
    const float* __restrict__ b_r, const float* __restrict__ b_i,
    const float* __restrict__ h_prev,       // [8192][4096] fp32
    float* __restrict__ out)                // [8192][4096] fp32
{
    __shared__ unsigned short As[256 * 32];   // 16 KB
    __shared__ unsigned short Bs[128 * 32];   // 8 KB

    const int tid  = threadIdx.x;
    const int wave = tid >> 6;
    const int lane = tid & 63;
    const int m0 = blockIdx.x * 256;
    const int n0 = blockIdx.y * 32;

    f32x16 acc[2][4];
#pragma unroll
    for (int i = 0; i < 2; ++i)
#pragma unroll
        for (int j = 0; j < 4; ++j)
#pragma unroll
            for (int r = 0; r < 16; ++r) acc[i][j][r] = 0.f;

    // ---- staging addressing ----
    // lane stages 16B chunk: row = blk + 16j + (lane>>2); LDS slot = lane&3 holds
    // global chunk (lane&3) ^ ((lane>>3)&3)  [swizzle: slot = c ^ ((row>>1)&3)]
    const int srow = lane >> 2;
    const int scol = ((lane & 3) ^ ((lane >> 3) & 3)) * 8;
    const unsigned short* Ag = E + (size_t)(m0 + wave * 64 + srow) * 2048 + scol;
    unsigned short* Al = As + (wave * 64) * 32;
    // Bs row rb in [0,128): chunk = rb>>5, W_cat row = (rb>>5)*2048 + n0 + (rb&31).
    // wave w stages rb in [w*32, w*32+32) -> chunk w.
    const unsigned short* Bg = W + (size_t)(wave * 2048 + n0 + srow) * 2048 + scol;
    unsigned short* Bl = Bs + (wave * 32) * 32;

    // ---- fragment addressing (32x32x16: A[m=lane&31][k=(lane>>5)*8+j]) ----
    const int L  = lane & 31;
    const int hi = lane >> 5;
    const int sw = (L >> 1) & 3;
    const int s0off = (hi ^ sw) * 8;         // slot for chunk c = hi     (k 0..15)
    const int s1off = ((hi ^ 2) ^ sw) * 8;   // slot for chunk c = 2+hi   (k 16..31)
    const unsigned short* ApL = As + (size_t)(wave * 64 + L) * 32;
    const unsigned short* BpL = Bs + (size_t)L * 32;

#pragma unroll 1
    for (int kt = 0; kt < 64; ++kt) {
        const int k0 = kt * 32;
#pragma unroll
        for (int j = 0; j < 4; ++j) load16_lds(Ag + (size_t)j * 16 * 2048 + k0, Al + j * 16 * 32);
#pragma unroll
        for (int j = 0; j < 2; ++j) load16_lds(Bg + (size_t)j * 16 * 2048 + k0, Bl + j * 16 * 32);
        __syncthreads();

        bf16x8 a[2][2], b[4][2];
#pragma unroll
        for (int ti = 0; ti < 2; ++ti) {
            a[ti][0] = ldfrag(ApL + ti * 32 * 32 + s0off);
            a[ti][1] = ldfrag(ApL + ti * 32 * 32 + s1off);
        }
#pragma unroll
        for (int tj = 0; tj < 4; ++tj) {
            b[tj][0] = ldfrag(BpL + tj * 32 * 32 + s0off);
            b[tj][1] = ldfrag(BpL + tj * 32 * 32 + s1off);
        }

#pragma unroll
        for (int tj = 0; tj < 4; ++tj)
#pragma unroll
            for (int ti = 0; ti < 2; ++ti)
                acc[ti][tj] = __builtin_amdgcn_mfma_f32_32x32x16_bf16(a[ti][0], b[tj][0], acc[ti][tj], 0, 0, 0);
#pragma unroll
        for (int tj = 0; tj < 4; ++tj)
#pragma unroll
            for (int ti = 0; ti < 2; ++ti)
                acc[ti][tj] = __builtin_amdgcn_mfma_f32_32x32x16_bf16(a[ti][1], b[tj][1], acc[ti][tj], 0, 0, 0);
        __syncthreads();
    }

    // ---- fused epilogue ----
    // C/D 32x32: col = lane&31, row = 4*(lane>>5) + (reg&3) + 8*(reg>>2)
    // acc[ti][0]=p_lin, [1]=theta, [2]=inp_re, [3]=inp_im  (same row/col per reg)
    const int col = n0 + L;
    const float bp = b_p[col], bt = b_th[col], br = b_r[col], bi = b_i[col];
    const int rowb = m0 + wave * 64 + 4 * hi;
#pragma unroll
    for (int ti = 0; ti < 2; ++ti) {
#pragma unroll
        for (int r = 0; r < 16; ++r) {
            const int row = rowb + ti * 32 + (r & 3) + 8 * (r >> 2);
            const float pl  = acc[ti][0][r] + bp;
            const float th  = acc[ti][1][r] + bt;
            const float ire = acc[ti][2][r] + br;
            const float iim = acc[ti][3][r] + bi;
            const float p = 1.f / (1.f + __expf(-pl));
            float s, ct;
            __sincosf(th, &s, &ct);
            const size_t base = (size_t)row * 4096 + col;
            const float hre = h_prev[base];
            const float him = h_prev[base + 2048];
            const float rre = ct * hre - s * him;
            const float rim = s * hre + ct * him;
            out[base]        = (1.f - p) * rre + p * ire;
            out[base + 2048] = (1.f - p) * rim + p * iim;
        }
    }
}

extern "C" void kernel_launch(void* const* d_in, const int* in_sizes, int n_in,
                              void* d_out, int out_size, void* d_ws, size_t ws_size,
                              hipStream_t stream) {
    (void)in_sizes; (void)n_in; (void)out_size; (void)ws_size;
    const float* e_t   = (const float*)d_in[0];
    const float* h_prv = (const float*)d_in[1];
    const float* W_p   = (const float*)d_in[2];
    const float* b_p   = (const float*)d_in[3];
    const float* W_th  = (const float*)d_in[4];
    const float* b_th  = (const float*)d_in[5];
    const float* W_r   = (const float*)d_in[6];
    const float* b_r   = (const float*)d_in[7];
    const float* W_i   = (const float*)d_in[8];
    const float* b_i   = (const float*)d_in[9];
    float* out = (float*)d_out;

    // workspace: W_cat bf16 [8192][2048] (32MB) then E bf16 [8192][2048] (32MB)
    unsigned short* Wbf = (unsigned short*)d_ws;
    unsigned short* Ebf = Wbf + (size_t)8192 * 2048;

    cvt_all<<<16384, 256, 0, stream>>>(W_p, W_th, W_r, W_i, e_t, Wbf, Ebf);

    dim3 grid(32, 64);   // x: m-tiles (256 rows), y: d-col tiles (32 cols)
    mipt_main<<<grid, 256, 0, stream>>>(Ebf, Wbf, b_p, b_th, b_r, b_i, h_prv, out);
}